// Round 16
// baseline (353.540 us; speedup 1.0000x reference)
//
#include <hip/hip_runtime.h>
#include <math.h>
#include <stddef.h>

#define BB 4
#define LL 1024
#define DM 512
#define ED 1024
#define NST 16
#define DTR 32
#define XDBC 64
#define BL (BB*LL)   // 4096
#define CS 8         // scan chunk length
#define NC 128       // chunks per sequence (LL/CS)
#define XKS 16       // x_proj K-slices
#define XPAD 68      // x_proj LDS stride (floats)

typedef __attribute__((ext_vector_type(8))) short bf16x8;
typedef __attribute__((ext_vector_type(4))) float f32x4;
typedef unsigned short ushort_t;

__device__ __forceinline__ float silu_f(float x) { return x / (1.f + __expf(-x)); }

__device__ __forceinline__ ushort_t f2b(float f) {
    unsigned int u = __float_as_uint(f);
    unsigned int r = (u + 0x7FFFu + ((u >> 16) & 1u)) >> 16;
    return (ushort_t)r;
}
__device__ __forceinline__ float b2f(ushort_t v) {
    return __uint_as_float(((unsigned int)v) << 16);
}
__device__ __forceinline__ ushort_t f2h(float f) {
    _Float16 h = (_Float16)f;
    return *(ushort_t*)&h;
}
__device__ __forceinline__ float h2f(ushort_t v) {
    _Float16 h = *(_Float16*)&v;
    return (float)h;
}

__device__ __forceinline__ void gload16(const ushort_t* g, ushort_t* l) {
    __builtin_amdgcn_global_load_lds(
        (const __attribute__((address_space(1))) unsigned int*)g,
        (__attribute__((address_space(3))) unsigned int*)l, 16, 0, 0);
}

// ---------------- init: embedding + both weight cvt in one dispatch
__global__ void k_init(const float* __restrict__ x, const float* __restrict__ embW,
                       const float* __restrict__ embB, float* __restrict__ h,
                       const float* __restrict__ ipW, const float* __restrict__ opW,
                       ushort_t* __restrict__ wip, ushort_t* __restrict__ wop,
                       int nEmb, int n1, int n2) {
    int i = blockIdx.x * 256 + threadIdx.x;
    if (i < nEmb) {
        int d = i % DM, r = i / DM;
        h[i] = x[r * 2 + 0] * embW[d * 2 + 0] + x[r * 2 + 1] * embW[d * 2 + 1] + embB[d];
        return;
    }
    i -= nEmb;
    const float* src; ushort_t* dst; int q;
    if (i < n1) { src = ipW; dst = wip; q = i; }
    else if (i < n1 + n2) { src = opW; dst = wop; q = i - n1; }
    else return;
    float4 v = *(const float4*)(src + (size_t)q * 4);
    ushort_t o[4] = {f2b(v.x), f2b(v.y), f2b(v.z), f2b(v.w)};
    *(uint2*)(dst + (size_t)q * 4) = *(uint2*)o;
}

// ---------------- rmsnorm over rows of 512; per-layer variant also zeroes
// its row of xdb (for cxp's atomic accumulation).
template <int BF16OUT>
__global__ __launch_bounds__(256) void k_rmsnorm(const float* __restrict__ in,
                                                 const float* __restrict__ w,
                                                 void* __restrict__ outp,
                                                 float* __restrict__ xdbz) {
    int m = blockIdx.x;
    int tid = threadIdx.x;
    if (BF16OUT) {
        if (tid < 16)
            *(float4*)(xdbz + (size_t)m * XDBC + tid * 4) = make_float4(0.f, 0.f, 0.f, 0.f);
    }
    const float* row = in + (size_t)m * DM;
    float2 v = *(const float2*)(row + tid * 2);
    float ss = v.x * v.x + v.y * v.y;
    #pragma unroll
    for (int o = 32; o > 0; o >>= 1) ss += __shfl_down(ss, o, 64);
    __shared__ float red[4];
    int wid = tid >> 6;
    if ((tid & 63) == 0) red[wid] = ss;
    __syncthreads();
    float tot = red[0] + red[1] + red[2] + red[3];
    float rs = rsqrtf(tot * (1.f / DM) + 1e-5f);
    float2 wv = *(const float2*)(w + tid * 2);
    float ox = v.x * rs * wv.x;
    float oy = v.y * rs * wv.y;
    if (BF16OUT) {
        ushort_t o[2] = {f2b(ox), f2b(oy)};
        *(unsigned int*)((ushort_t*)outp + (size_t)m * DM + tid * 2) = *(unsigned int*)o;
    } else {
        *(float2*)((float*)outp + (size_t)m * DM + tid * 2) = make_float2(ox, oy);
    }
}

// ---------------- bf16 MFMA GEMM (round-12 structure, unchanged)
template <int ADDRES, int BF16OUT, int NT>
__global__ __launch_bounds__(256) void k_bgemm(const ushort_t* __restrict__ A,
                                               const ushort_t* __restrict__ W,
                                               const float* __restrict__ Res,
                                               void* __restrict__ C,
                                               int M, int N, int K, int lda, int ldc) {
    __shared__ ushort_t As[128 * 32];
    __shared__ ushort_t Bs[NT * 32];
    constexpr int NFJ = NT / 32;
    int tid = threadIdx.x;
    int bm = blockIdx.y * 128, bn = blockIdx.x * NT;
    int wave = tid >> 6, lane = tid & 63;
    int wr = wave >> 1, wc = wave & 1;
    int lr = lane & 15;
    int kc = lane >> 4;
    f32x4 acc[4][NFJ];
    #pragma unroll
    for (int i = 0; i < 4; ++i)
        #pragma unroll
        for (int j = 0; j < NFJ; ++j) acc[i][j] = (f32x4){0.f, 0.f, 0.f, 0.f};

    for (int k0 = 0; k0 < K; k0 += 32) {
        __syncthreads();
        #pragma unroll
        for (int ii = 0; ii < 2; ++ii) {
            int g = wave * 128 + ii * 64 + lane;
            int row = g >> 2;
            int c = (g & 3) ^ ((g >> 3) & 3);
            gload16(A + (size_t)(bm + row) * lda + k0 + c * 8,
                    As + (size_t)(wave * 128 + ii * 64) * 8);
        }
        #pragma unroll
        for (int ii = 0; ii < NFJ / 2; ++ii) {
            int g = wave * (NFJ / 2) * 64 + ii * 64 + lane;
            int row = g >> 2;
            int c = (g & 3) ^ ((g >> 3) & 3);
            gload16(W + (size_t)(bn + row) * K + k0 + c * 8,
                    Bs + (size_t)(wave * (NFJ / 2) * 64 + ii * 64) * 8);
        }
        __syncthreads();
        bf16x8 af[4], bfr[NFJ];
        #pragma unroll
        for (int i = 0; i < 4; ++i) {
            int ra = wr * 64 + i * 16 + lr;
            int ca = kc ^ ((ra >> 1) & 3);
            af[i] = *(const bf16x8*)(As + ra * 32 + ca * 8);
        }
        #pragma unroll
        for (int j = 0; j < NFJ; ++j) {
            int rb = wc * (NT / 2) + j * 16 + lr;
            int cb = kc ^ ((rb >> 1) & 3);
            bfr[j] = *(const bf16x8*)(Bs + rb * 32 + cb * 8);
        }
        #pragma unroll
        for (int i = 0; i < 4; ++i)
            #pragma unroll
            for (int j = 0; j < NFJ; ++j)
                acc[i][j] = __builtin_amdgcn_mfma_f32_16x16x32_bf16(af[i], bfr[j], acc[i][j], 0, 0, 0);
    }
    int crow0 = bm + wr * 64 + (lane >> 4) * 4;
    #pragma unroll
    for (int i = 0; i < 4; ++i)
        #pragma unroll
        for (int j = 0; j < NFJ; ++j)
            #pragma unroll
            for (int r = 0; r < 4; ++r) {
                size_t off = (size_t)(crow0 + i * 16 + r) * ldc + bn + wc * (NT / 2) + j * 16 + lr;
                float v = acc[i][j][r];
                if (ADDRES) v += Res[off];
                if (BF16OUT) ((ushort_t*)C)[off] = f2b(v);
                else         ((float*)C)[off] = v;
            }
}

// ---------------- fused conv+silu -> x_proj split-K; partials accumulated
// directly into xdb via fp32 atomicAdd (xdb pre-zeroed by k_rmsnorm).
__global__ __launch_bounds__(256) void k_cxp(const ushort_t* __restrict__ xzb,
                                             const float* __restrict__ cw,
                                             const float* __restrict__ cb,
                                             const float* __restrict__ xpW,
                                             ushort_t* __restrict__ ub,
                                             float* __restrict__ xdb) {
    __shared__ float As[64][XPAD];   // [e-within-slice][row]
    __shared__ float Ws[64][XPAD];   // [e-within-slice][n]
    int tid = threadIdx.x;
    int ks = blockIdx.x;
    int bm = blockIdx.y * 64;
    int ec0 = ks * 64;

    {
        int r0 = (tid >> 4) * 4;
        int e4 = (tid & 15) * 4;
        int e = ec0 + e4;
        float cw4[4][4], cb4[4];
        #pragma unroll
        for (int j = 0; j < 4; ++j) {
            float4 w = *(const float4*)(cw + (size_t)(e + j) * 4);
            cw4[j][0] = w.x; cw4[j][1] = w.y; cw4[j][2] = w.z; cw4[j][3] = w.w;
        }
        float4 cbv = *(const float4*)(cb + e);
        cb4[0] = cbv.x; cb4[1] = cbv.y; cb4[2] = cbv.z; cb4[3] = cbv.w;
        #pragma unroll
        for (int i = 0; i < 4; ++i) {
            int row = bm + r0 + i;
            int tloc = row & (LL - 1);
            const ushort_t* xrow = xzb + (size_t)row * 2048 + e;
            uint2 z2 = make_uint2(0, 0);
            uint2 v3 = *(const uint2*)xrow;
            uint2 v2 = (tloc >= 1) ? *(const uint2*)(xrow - 2048) : z2;
            uint2 v1 = (tloc >= 2) ? *(const uint2*)(xrow - 4096) : z2;
            uint2 v0 = (tloc >= 3) ? *(const uint2*)(xrow - 6144) : z2;
            const ushort_t* p0 = (const ushort_t*)&v0;
            const ushort_t* p1 = (const ushort_t*)&v1;
            const ushort_t* p2 = (const ushort_t*)&v2;
            const ushort_t* p3 = (const ushort_t*)&v3;
            ushort_t ures[4];
            #pragma unroll
            for (int j = 0; j < 4; ++j) {
                float a = cb4[j] + b2f(p0[j]) * cw4[j][0] + b2f(p1[j]) * cw4[j][1]
                                 + b2f(p2[j]) * cw4[j][2] + b2f(p3[j]) * cw4[j][3];
                float uu = silu_f(a);
                As[e4 + j][r0 + i] = uu;
                ures[j] = f2b(uu);
            }
            *(uint2*)(ub + (size_t)row * ED + e) = *(uint2*)ures;
        }
    }
    {
        int r = tid >> 2;
        int kc = (tid & 3) * 16;
        const float4* wp = (const float4*)(xpW + (size_t)r * ED + ec0 + kc);
        #pragma unroll
        for (int i = 0; i < 4; ++i) {
            float4 wv = wp[i];
            Ws[kc + i * 4 + 0][r] = wv.x; Ws[kc + i * 4 + 1][r] = wv.y;
            Ws[kc + i * 4 + 2][r] = wv.z; Ws[kc + i * 4 + 3][r] = wv.w;
        }
    }
    __syncthreads();
    int tm = (tid >> 4) * 4;
    int tn = (tid & 15) * 4;
    float acc[4][4] = {};
    #pragma unroll 4
    for (int k = 0; k < 64; ++k) {
        float4 a = *(const float4*)&As[k][tm];
        float4 b = *(const float4*)&Ws[k][tn];
        acc[0][0] += a.x * b.x; acc[0][1] += a.x * b.y; acc[0][2] += a.x * b.z; acc[0][3] += a.x * b.w;
        acc[1][0] += a.y * b.x; acc[1][1] += a.y * b.y; acc[1][2] += a.y * b.z; acc[1][3] += a.y * b.w;
        acc[2][0] += a.z * b.x; acc[2][1] += a.z * b.y; acc[2][2] += a.z * b.z; acc[2][3] += a.z * b.w;
        acc[3][0] += a.w * b.x; acc[3][1] += a.w * b.y; acc[3][2] += a.w * b.z; acc[3][3] += a.w * b.w;
    }
    #pragma unroll
    for (int i = 0; i < 4; ++i)
        #pragma unroll
        for (int j = 0; j < 4; ++j)
            atomicAdd(xdb + (size_t)(bm + tm + i) * XDBC + tn + j, acc[i][j]);
}

// ================ chunked selective scan (CS=8, NC=128) ================
// scan1: parallel delta precompute (stored fp16 for scan3), chunk-local scan,
// bf16 chunk states.
__global__ __launch_bounds__(256) void k_scan1(const float* __restrict__ xdb,
                                               const ushort_t* __restrict__ u,
                                               const float* __restrict__ dtW,
                                               const float* __restrict__ dtb,
                                               const float* __restrict__ A_log,
                                               ushort_t* __restrict__ P,
                                               float* __restrict__ S,
                                               ushort_t* __restrict__ dyh) {
    __shared__ float Xs[CS][XDBC];   // 2 KB
    int tid = threadIdx.x;
    int e = ((blockIdx.x & 3) << 8) + tid;
    int c = (blockIdx.x >> 2) & (NC - 1);
    int b = blockIdx.x >> 9;
    size_t r0 = (size_t)b * LL + c * CS;
    {
        int t = tid >> 5, q = (tid & 31) * 2;
        *(float2*)&Xs[t][q] = *(const float2*)(xdb + (r0 + t) * XDBC + q);
    }
    float Ac[16];
    const float4* ap = (const float4*)(A_log + (size_t)e * NST);
    #pragma unroll
    for (int q = 0; q < 4; ++q) {
        float4 a = ap[q];
        Ac[q * 4 + 0] = -__expf(a.x); Ac[q * 4 + 1] = -__expf(a.y);
        Ac[q * 4 + 2] = -__expf(a.z); Ac[q * 4 + 3] = -__expf(a.w);
    }
    float dtw[32];
    const float4* wq = (const float4*)(dtW + (size_t)e * DTR);
    #pragma unroll
    for (int q = 0; q < 8; ++q) {
        float4 w = wq[q];
        dtw[q * 4 + 0] = w.x; dtw[q * 4 + 1] = w.y;
        dtw[q * 4 + 2] = w.z; dtw[q * 4 + 3] = w.w;
    }
    float bias = dtb[e];
    __syncthreads();
    float dv[CS];
    #pragma unroll
    for (int t = 0; t < CS; ++t) {
        float acc = bias;
        #pragma unroll
        for (int q = 0; q < 8; ++q) {
            float4 d = *(const float4*)&Xs[t][q * 4];
            acc += d.x * dtw[q * 4 + 0] + d.y * dtw[q * 4 + 1] +
                   d.z * dtw[q * 4 + 2] + d.w * dtw[q * 4 + 3];
        }
        dv[t] = (acc > 20.f) ? acc : __logf(1.f + __expf(acc));
        dyh[(r0 + t) * ED + e] = f2h(dv[t]);
    }
    float h[16] = {};
    float s = 0.f;
    const ushort_t* up = u + r0 * ED + e;
    for (int tt = 0; tt < CS; ++tt) {
        float d = dv[tt];
        float uv = b2f(up[(size_t)tt * ED]);
        s += d;
        float du = d * uv;
        const float4* bp = (const float4*)&Xs[tt][DTR];
        #pragma unroll
        for (int q = 0; q < 4; ++q) {
            float4 bv = bp[q];
            h[q * 4 + 0] = __expf(d * Ac[q * 4 + 0]) * h[q * 4 + 0] + du * bv.x;
            h[q * 4 + 1] = __expf(d * Ac[q * 4 + 1]) * h[q * 4 + 1] + du * bv.y;
            h[q * 4 + 2] = __expf(d * Ac[q * 4 + 2]) * h[q * 4 + 2] + du * bv.z;
            h[q * 4 + 3] = __expf(d * Ac[q * 4 + 3]) * h[q * 4 + 3] + du * bv.w;
        }
    }
    ushort_t pb[16];
    #pragma unroll
    for (int n = 0; n < 16; ++n) pb[n] = f2b(h[n]);
    uint4* pp = (uint4*)(P + ((size_t)(b * NC + c) * ED + e) * NST);
    pp[0] = ((uint4*)pb)[0];
    pp[1] = ((uint4*)pb)[1];
    S[(size_t)(b * NC + c) * ED + e] = s;
}

__global__ __launch_bounds__(256) void k_scan2(ushort_t* __restrict__ P,
                                               const float* __restrict__ S,
                                               const float* __restrict__ A_log) {
    int i = blockIdx.x * 256 + threadIdx.x;
    int n = i & 15;
    int e = (i >> 4) & (ED - 1);
    int b = i >> 14;
    float Ac = -__expf(A_log[(size_t)e * NST + n]);
    float hin = 0.f;
    for (int c = 0; c < NC; ++c) {
        size_t base = (size_t)(b * NC + c) * ED + e;
        float p = b2f(P[base * NST + n]);
        float s = S[base];
        P[base * NST + n] = f2b(hin);
        hin = __expf(Ac * s) * hin + p;
    }
}

// scan3: re-scan with h_in using stored fp16 delta; fused silu(z); bf16 yb.
__global__ __launch_bounds__(256) void k_scan3(const float* __restrict__ xdb,
                                               const ushort_t* __restrict__ u,
                                               const ushort_t* __restrict__ xzb,
                                               const ushort_t* __restrict__ dyh,
                                               const float* __restrict__ A_log,
                                               const float* __restrict__ Dskip,
                                               const ushort_t* __restrict__ P,
                                               ushort_t* __restrict__ yb) {
    __shared__ float Xs[CS][XDBC];
    int tid = threadIdx.x;
    int e = ((blockIdx.x & 3) << 8) + tid;
    int c = (blockIdx.x >> 2) & (NC - 1);
    int b = blockIdx.x >> 9;
    size_t r0 = (size_t)b * LL + c * CS;
    {
        int t = tid >> 5, q = (tid & 31) * 2;
        *(float2*)&Xs[t][q] = *(const float2*)(xdb + (r0 + t) * XDBC + q);
    }
    float Ac[16];
    const float4* ap = (const float4*)(A_log + (size_t)e * NST);
    #pragma unroll
    for (int q = 0; q < 4; ++q) {
        float4 a = ap[q];
        Ac[q * 4 + 0] = -__expf(a.x); Ac[q * 4 + 1] = -__expf(a.y);
        Ac[q * 4 + 2] = -__expf(a.z); Ac[q * 4 + 3] = -__expf(a.w);
    }
    float h[16];
    const uint4* pp4 = (const uint4*)(P + ((size_t)(b * NC + c) * ED + e) * NST);
    uint4 pA = pp4[0], pB = pp4[1];
    const ushort_t* pw0 = (const ushort_t*)&pA;
    const ushort_t* pw1 = (const ushort_t*)&pB;
    #pragma unroll
    for (int n = 0; n < 8; ++n) { h[n] = b2f(pw0[n]); h[8 + n] = b2f(pw1[n]); }
    float Dk = Dskip[e];
    __syncthreads();
    const ushort_t* dp = dyh + r0 * ED + e;
    const ushort_t* up = u + r0 * ED + e;
    const ushort_t* zp = xzb + r0 * 2048 + 1024 + e;
    ushort_t* yp = yb + r0 * ED + e;
    for (int tt = 0; tt < CS; ++tt) {
        float d = h2f(dp[(size_t)tt * ED]);
        float uv = b2f(up[(size_t)tt * ED]);
        float zv = b2f(zp[(size_t)tt * 2048]);
        float du = d * uv;
        const float4* bp = (const float4*)&Xs[tt][DTR];
        const float4* cp = (const float4*)&Xs[tt][DTR + NST];
        float y = 0.f;
        #pragma unroll
        for (int q = 0; q < 4; ++q) {
            float4 bv = bp[q];
            float4 cv = cp[q];
            h[q * 4 + 0] = __expf(d * Ac[q * 4 + 0]) * h[q * 4 + 0] + du * bv.x;
            h[q * 4 + 1] = __expf(d * Ac[q * 4 + 1]) * h[q * 4 + 1] + du * bv.y;
            h[q * 4 + 2] = __expf(d * Ac[q * 4 + 2]) * h[q * 4 + 2] + du * bv.z;
            h[q * 4 + 3] = __expf(d * Ac[q * 4 + 3]) * h[q * 4 + 3] + du * bv.w;
            y += h[q * 4 + 0] * cv.x + h[q * 4 + 1] * cv.y +
                 h[q * 4 + 2] * cv.z + h[q * 4 + 3] * cv.w;
        }
        yp[(size_t)tt * ED] = f2b((y + Dk * uv) * silu_f(zv));
    }
}

extern "C" void kernel_launch(void* const* d_in, const int* in_sizes, int n_in,
                              void* d_out, int out_size, void* d_ws, size_t ws_size,
                              hipStream_t stream) {
    const float* x     = (const float*)d_in[0];
    const float* embW  = (const float*)d_in[1];
    const float* embB  = (const float*)d_in[2];
    const float* normw = (const float*)d_in[3];
    const float* ipW   = (const float*)d_in[4];
    const float* cW    = (const float*)d_in[5];
    const float* cb    = (const float*)d_in[6];
    const float* xpW   = (const float*)d_in[7];
    const float* dtW   = (const float*)d_in[8];
    const float* dtb   = (const float*)d_in[9];
    const float* Alog  = (const float*)d_in[10];
    const float* Dsk   = (const float*)d_in[11];
    const float* opW   = (const float*)d_in[12];
    const float* normfw= (const float*)d_in[13];
    float* out = (float*)d_out;

    // ws: h 8MB | xzb 16 | ub 8 | xdb 1 | P(bf16) 16 | S 2 | wip 4 | wop 2
    //     | yb 8  = 65 MB
    float* ws  = (float*)d_ws;
    float* h   = ws;
    ushort_t* xzb = (ushort_t*)(h + (size_t)BL * DM);
    ushort_t* ub  = xzb + (size_t)BL * 2 * ED;
    float* xdb = (float*)(ub + (size_t)BL * ED);
    ushort_t* P = (ushort_t*)(xdb + (size_t)BL * XDBC);
    float* S   = (float*)(P + (size_t)BB * NC * ED * NST);
    ushort_t* wip = (ushort_t*)(S + (size_t)BB * NC * ED);
    ushort_t* wop = wip + (size_t)2 * 2 * ED * DM;
    ushort_t* yb  = wop + (size_t)2 * DM * ED;
    ushort_t* hnb = (ushort_t*)d_out;   // bf16 rmsnorm scratch (d_out reuse)
    ushort_t* dyh = (ushort_t*)d_out;   // fp16 delta (post-bgemm0 window)

    int nEmb = BL * DM;
    int n1 = 2 * 2 * ED * DM / 4, n2 = 2 * DM * ED / 4;
    k_init<<<(nEmb + n1 + n2 + 255) / 256, 256, 0, stream>>>(
        x, embW, embB, h, ipW, opW, wip, wop, nEmb, n1, n2);

    for (int l = 0; l < 2; ++l) {
        const float* Al = Alog + (size_t)l * ED * NST;
        const float* dtWl = dtW + (size_t)l * ED * DTR;
        const float* dtbl = dtb + (size_t)l * ED;
        k_rmsnorm<1><<<BL, 256, 0, stream>>>(h, normw + (size_t)l * DM, hnb, xdb);
        k_bgemm<0, 1, 128><<<dim3(2 * ED / 128, BL / 128), 256, 0, stream>>>(
            hnb, wip + (size_t)l * 2 * ED * DM, nullptr, xzb, BL, 2 * ED, DM, DM, 2 * ED);
        k_cxp<<<dim3(XKS, BL / 64), 256, 0, stream>>>(
            xzb, cW + (size_t)l * ED * 4, cb + (size_t)l * ED,
            xpW + (size_t)l * XDBC * ED, ub, xdb);
        k_scan1<<<BB * NC * (ED / 256), 256, 0, stream>>>(
            xdb, ub, dtWl, dtbl, Al, P, S, dyh);
        k_scan2<<<BB * ED * NST / 256, 256, 0, stream>>>(P, S, Al);
        k_scan3<<<BB * NC * (ED / 256), 256, 0, stream>>>(
            xdb, ub, xzb, dyh, Al, Dsk + (size_t)l * ED, P, yb);
        k_bgemm<1, 0, 64><<<dim3(DM / 64, BL / 128), 256, 0, stream>>>(
            yb, wop + (size_t)l * DM * ED, h, h, BL, DM, ED, ED, DM);
    }
    k_rmsnorm<0><<<BL, 256, 0, stream>>>(h, normfw, out, nullptr);
}

// Round 17
// 272.784 us; speedup vs baseline: 1.2960x; 1.2960x over previous
//
#include <hip/hip_runtime.h>
#include <math.h>
#include <stddef.h>

#define BB 4
#define LL 1024
#define DM 512
#define ED 1024
#define NST 16
#define DTR 32
#define XDBC 64
#define BL (BB*LL)   // 4096
#define CS 8         // scan chunk length
#define NC 128       // chunks per sequence (LL/CS)
#define XKS 16       // x_proj K-slices
#define XPAD 68      // x_proj LDS stride (floats)

typedef __attribute__((ext_vector_type(8))) short bf16x8;
typedef __attribute__((ext_vector_type(4))) float f32x4;
typedef unsigned short ushort_t;

__device__ __forceinline__ float silu_f(float x) { return x / (1.f + __expf(-x)); }

__device__ __forceinline__ ushort_t f2b(float f) {
    unsigned int u = __float_as_uint(f);
    unsigned int r = (u + 0x7FFFu + ((u >> 16) & 1u)) >> 16;
    return (ushort_t)r;
}
__device__ __forceinline__ float b2f(ushort_t v) {
    return __uint_as_float(((unsigned int)v) << 16);
}
__device__ __forceinline__ ushort_t f2h(float f) {
    _Float16 h = (_Float16)f;
    return *(ushort_t*)&h;
}
__device__ __forceinline__ float h2f(ushort_t v) {
    _Float16 h = *(_Float16*)&v;
    return (float)h;
}

__device__ __forceinline__ void gload16(const ushort_t* g, ushort_t* l) {
    __builtin_amdgcn_global_load_lds(
        (const __attribute__((address_space(1))) unsigned int*)g,
        (__attribute__((address_space(3))) unsigned int*)l, 16, 0, 0);
}

// ---------------- init: embedding + both weight cvt in one dispatch
__global__ void k_init(const float* __restrict__ x, const float* __restrict__ embW,
                       const float* __restrict__ embB, float* __restrict__ h,
                       const float* __restrict__ ipW, const float* __restrict__ opW,
                       ushort_t* __restrict__ wip, ushort_t* __restrict__ wop,
                       int nEmb, int n1, int n2) {
    int i = blockIdx.x * 256 + threadIdx.x;
    if (i < nEmb) {
        int d = i % DM, r = i / DM;
        h[i] = x[r * 2 + 0] * embW[d * 2 + 0] + x[r * 2 + 1] * embW[d * 2 + 1] + embB[d];
        return;
    }
    i -= nEmb;
    const float* src; ushort_t* dst; int q;
    if (i < n1) { src = ipW; dst = wip; q = i; }
    else if (i < n1 + n2) { src = opW; dst = wop; q = i - n1; }
    else return;
    float4 v = *(const float4*)(src + (size_t)q * 4);
    ushort_t o[4] = {f2b(v.x), f2b(v.y), f2b(v.z), f2b(v.w)};
    *(uint2*)(dst + (size_t)q * 4) = *(uint2*)o;
}

// ---------------- rmsnorm over rows of 512
template <int BF16OUT>
__global__ __launch_bounds__(256) void k_rmsnorm(const float* __restrict__ in,
                                                 const float* __restrict__ w,
                                                 void* __restrict__ outp) {
    int m = blockIdx.x;
    int tid = threadIdx.x;
    const float* row = in + (size_t)m * DM;
    float2 v = *(const float2*)(row + tid * 2);
    float ss = v.x * v.x + v.y * v.y;
    #pragma unroll
    for (int o = 32; o > 0; o >>= 1) ss += __shfl_down(ss, o, 64);
    __shared__ float red[4];
    int wid = tid >> 6;
    if ((tid & 63) == 0) red[wid] = ss;
    __syncthreads();
    float tot = red[0] + red[1] + red[2] + red[3];
    float rs = rsqrtf(tot * (1.f / DM) + 1e-5f);
    float2 wv = *(const float2*)(w + tid * 2);
    float ox = v.x * rs * wv.x;
    float oy = v.y * rs * wv.y;
    if (BF16OUT) {
        ushort_t o[2] = {f2b(ox), f2b(oy)};
        *(unsigned int*)((ushort_t*)outp + (size_t)m * DM + tid * 2) = *(unsigned int*)o;
    } else {
        *(float2*)((float*)outp + (size_t)m * DM + tid * 2) = make_float2(ox, oy);
    }
}

// ---------------- bf16 MFMA GEMM (round-12 structure, unchanged)
template <int ADDRES, int BF16OUT, int NT>
__global__ __launch_bounds__(256) void k_bgemm(const ushort_t* __restrict__ A,
                                               const ushort_t* __restrict__ W,
                                               const float* __restrict__ Res,
                                               void* __restrict__ C,
                                               int M, int N, int K, int lda, int ldc) {
    __shared__ ushort_t As[128 * 32];
    __shared__ ushort_t Bs[NT * 32];
    constexpr int NFJ = NT / 32;
    int tid = threadIdx.x;
    int bm = blockIdx.y * 128, bn = blockIdx.x * NT;
    int wave = tid >> 6, lane = tid & 63;
    int wr = wave >> 1, wc = wave & 1;
    int lr = lane & 15;
    int kc = lane >> 4;
    f32x4 acc[4][NFJ];
    #pragma unroll
    for (int i = 0; i < 4; ++i)
        #pragma unroll
        for (int j = 0; j < NFJ; ++j) acc[i][j] = (f32x4){0.f, 0.f, 0.f, 0.f};

    for (int k0 = 0; k0 < K; k0 += 32) {
        __syncthreads();
        #pragma unroll
        for (int ii = 0; ii < 2; ++ii) {
            int g = wave * 128 + ii * 64 + lane;
            int row = g >> 2;
            int c = (g & 3) ^ ((g >> 3) & 3);
            gload16(A + (size_t)(bm + row) * lda + k0 + c * 8,
                    As + (size_t)(wave * 128 + ii * 64) * 8);
        }
        #pragma unroll
        for (int ii = 0; ii < NFJ / 2; ++ii) {
            int g = wave * (NFJ / 2) * 64 + ii * 64 + lane;
            int row = g >> 2;
            int c = (g & 3) ^ ((g >> 3) & 3);
            gload16(W + (size_t)(bn + row) * K + k0 + c * 8,
                    Bs + (size_t)(wave * (NFJ / 2) * 64 + ii * 64) * 8);
        }
        __syncthreads();
        bf16x8 af[4], bfr[NFJ];
        #pragma unroll
        for (int i = 0; i < 4; ++i) {
            int ra = wr * 64 + i * 16 + lr;
            int ca = kc ^ ((ra >> 1) & 3);
            af[i] = *(const bf16x8*)(As + ra * 32 + ca * 8);
        }
        #pragma unroll
        for (int j = 0; j < NFJ; ++j) {
            int rb = wc * (NT / 2) + j * 16 + lr;
            int cb = kc ^ ((rb >> 1) & 3);
            bfr[j] = *(const bf16x8*)(Bs + rb * 32 + cb * 8);
        }
        #pragma unroll
        for (int i = 0; i < 4; ++i)
            #pragma unroll
            for (int j = 0; j < NFJ; ++j)
                acc[i][j] = __builtin_amdgcn_mfma_f32_16x16x32_bf16(af[i], bfr[j], acc[i][j], 0, 0, 0);
    }
    int crow0 = bm + wr * 64 + (lane >> 4) * 4;
    #pragma unroll
    for (int i = 0; i < 4; ++i)
        #pragma unroll
        for (int j = 0; j < NFJ; ++j)
            #pragma unroll
            for (int r = 0; r < 4; ++r) {
                size_t off = (size_t)(crow0 + i * 16 + r) * ldc + bn + wc * (NT / 2) + j * 16 + lr;
                float v = acc[i][j][r];
                if (ADDRES) v += Res[off];
                if (BF16OUT) ((ushort_t*)C)[off] = f2b(v);
                else         ((float*)C)[off] = v;
            }
}

// ---------------- fused conv+silu -> x_proj split-K partial (round-14 form)
__global__ __launch_bounds__(256) void k_cxp(const ushort_t* __restrict__ xzb,
                                             const float* __restrict__ cw,
                                             const float* __restrict__ cb,
                                             const float* __restrict__ xpW,
                                             ushort_t* __restrict__ ub,
                                             float* __restrict__ Pp) {
    __shared__ float As[64][XPAD];   // [e-within-slice][row]
    __shared__ float Ws[64][XPAD];   // [e-within-slice][n]
    int tid = threadIdx.x;
    int ks = blockIdx.x;
    int bm = blockIdx.y * 64;
    int ec0 = ks * 64;

    {
        int r0 = (tid >> 4) * 4;
        int e4 = (tid & 15) * 4;
        int e = ec0 + e4;
        float cw4[4][4], cb4[4];
        #pragma unroll
        for (int j = 0; j < 4; ++j) {
            float4 w = *(const float4*)(cw + (size_t)(e + j) * 4);
            cw4[j][0] = w.x; cw4[j][1] = w.y; cw4[j][2] = w.z; cw4[j][3] = w.w;
        }
        float4 cbv = *(const float4*)(cb + e);
        cb4[0] = cbv.x; cb4[1] = cbv.y; cb4[2] = cbv.z; cb4[3] = cbv.w;
        #pragma unroll
        for (int i = 0; i < 4; ++i) {
            int row = bm + r0 + i;
            int tloc = row & (LL - 1);
            const ushort_t* xrow = xzb + (size_t)row * 2048 + e;
            uint2 z2 = make_uint2(0, 0);
            uint2 v3 = *(const uint2*)xrow;
            uint2 v2 = (tloc >= 1) ? *(const uint2*)(xrow - 2048) : z2;
            uint2 v1 = (tloc >= 2) ? *(const uint2*)(xrow - 4096) : z2;
            uint2 v0 = (tloc >= 3) ? *(const uint2*)(xrow - 6144) : z2;
            const ushort_t* p0 = (const ushort_t*)&v0;
            const ushort_t* p1 = (const ushort_t*)&v1;
            const ushort_t* p2 = (const ushort_t*)&v2;
            const ushort_t* p3 = (const ushort_t*)&v3;
            ushort_t ures[4];
            #pragma unroll
            for (int j = 0; j < 4; ++j) {
                float a = cb4[j] + b2f(p0[j]) * cw4[j][0] + b2f(p1[j]) * cw4[j][1]
                                 + b2f(p2[j]) * cw4[j][2] + b2f(p3[j]) * cw4[j][3];
                float uu = silu_f(a);
                As[e4 + j][r0 + i] = uu;
                ures[j] = f2b(uu);
            }
            *(uint2*)(ub + (size_t)row * ED + e) = *(uint2*)ures;
        }
    }
    {
        int r = tid >> 2;
        int kc = (tid & 3) * 16;
        const float4* wp = (const float4*)(xpW + (size_t)r * ED + ec0 + kc);
        #pragma unroll
        for (int i = 0; i < 4; ++i) {
            float4 wv = wp[i];
            Ws[kc + i * 4 + 0][r] = wv.x; Ws[kc + i * 4 + 1][r] = wv.y;
            Ws[kc + i * 4 + 2][r] = wv.z; Ws[kc + i * 4 + 3][r] = wv.w;
        }
    }
    __syncthreads();
    int tm = (tid >> 4) * 4;
    int tn = (tid & 15) * 4;
    float acc[4][4] = {};
    #pragma unroll 4
    for (int k = 0; k < 64; ++k) {
        float4 a = *(const float4*)&As[k][tm];
        float4 b = *(const float4*)&Ws[k][tn];
        acc[0][0] += a.x * b.x; acc[0][1] += a.x * b.y; acc[0][2] += a.x * b.z; acc[0][3] += a.x * b.w;
        acc[1][0] += a.y * b.x; acc[1][1] += a.y * b.y; acc[1][2] += a.y * b.z; acc[1][3] += a.y * b.w;
        acc[2][0] += a.z * b.x; acc[2][1] += a.z * b.y; acc[2][2] += a.z * b.z; acc[2][3] += a.z * b.w;
        acc[3][0] += a.w * b.x; acc[3][1] += a.w * b.y; acc[3][2] += a.w * b.z; acc[3][3] += a.w * b.w;
    }
    float* pp = Pp + (size_t)ks * BL * XDBC;
    #pragma unroll
    for (int i = 0; i < 4; ++i)
        *(float4*)(pp + (size_t)(bm + tm + i) * XDBC + tn) =
            make_float4(acc[i][0], acc[i][1], acc[i][2], acc[i][3]);
}

// reduce 16 K-slice partials -> xdb
__global__ void k_xred(const float* __restrict__ Pp, float* __restrict__ xdb) {
    int i = blockIdx.x * 256 + threadIdx.x;
    float4 s = make_float4(0.f, 0.f, 0.f, 0.f);
    #pragma unroll
    for (int sl = 0; sl < XKS; ++sl) {
        float4 v = *(const float4*)(Pp + (size_t)sl * BL * XDBC + (size_t)i * 4);
        s.x += v.x; s.y += v.y; s.z += v.z; s.w += v.w;
    }
    *(float4*)(xdb + (size_t)i * 4) = s;
}

// ================ chunked selective scan (CS=8, NC=128) ================
// scan1: parallel delta precompute (stored fp16 for scan3), chunk-local scan,
// bf16 chunk states.
__global__ __launch_bounds__(256) void k_scan1(const float* __restrict__ xdb,
                                               const ushort_t* __restrict__ u,
                                               const float* __restrict__ dtW,
                                               const float* __restrict__ dtb,
                                               const float* __restrict__ A_log,
                                               ushort_t* __restrict__ P,
                                               float* __restrict__ S,
                                               ushort_t* __restrict__ dyh) {
    __shared__ float Xs[CS][XDBC];   // 2 KB
    int tid = threadIdx.x;
    int e = ((blockIdx.x & 3) << 8) + tid;
    int c = (blockIdx.x >> 2) & (NC - 1);
    int b = blockIdx.x >> 9;
    size_t r0 = (size_t)b * LL + c * CS;
    {
        int t = tid >> 5, q = (tid & 31) * 2;
        *(float2*)&Xs[t][q] = *(const float2*)(xdb + (r0 + t) * XDBC + q);
    }
    float Ac[16];
    const float4* ap = (const float4*)(A_log + (size_t)e * NST);
    #pragma unroll
    for (int q = 0; q < 4; ++q) {
        float4 a = ap[q];
        Ac[q * 4 + 0] = -__expf(a.x); Ac[q * 4 + 1] = -__expf(a.y);
        Ac[q * 4 + 2] = -__expf(a.z); Ac[q * 4 + 3] = -__expf(a.w);
    }
    float dtw[32];
    const float4* wq = (const float4*)(dtW + (size_t)e * DTR);
    #pragma unroll
    for (int q = 0; q < 8; ++q) {
        float4 w = wq[q];
        dtw[q * 4 + 0] = w.x; dtw[q * 4 + 1] = w.y;
        dtw[q * 4 + 2] = w.z; dtw[q * 4 + 3] = w.w;
    }
    float bias = dtb[e];
    __syncthreads();
    float dv[CS];
    #pragma unroll
    for (int t = 0; t < CS; ++t) {
        float acc = bias;
        #pragma unroll
        for (int q = 0; q < 8; ++q) {
            float4 d = *(const float4*)&Xs[t][q * 4];
            acc += d.x * dtw[q * 4 + 0] + d.y * dtw[q * 4 + 1] +
                   d.z * dtw[q * 4 + 2] + d.w * dtw[q * 4 + 3];
        }
        dv[t] = (acc > 20.f) ? acc : __logf(1.f + __expf(acc));
        dyh[(r0 + t) * ED + e] = f2h(dv[t]);
    }
    float h[16] = {};
    float s = 0.f;
    const ushort_t* up = u + r0 * ED + e;
    for (int tt = 0; tt < CS; ++tt) {
        float d = dv[tt];
        float uv = b2f(up[(size_t)tt * ED]);
        s += d;
        float du = d * uv;
        const float4* bp = (const float4*)&Xs[tt][DTR];
        #pragma unroll
        for (int q = 0; q < 4; ++q) {
            float4 bv = bp[q];
            h[q * 4 + 0] = __expf(d * Ac[q * 4 + 0]) * h[q * 4 + 0] + du * bv.x;
            h[q * 4 + 1] = __expf(d * Ac[q * 4 + 1]) * h[q * 4 + 1] + du * bv.y;
            h[q * 4 + 2] = __expf(d * Ac[q * 4 + 2]) * h[q * 4 + 2] + du * bv.z;
            h[q * 4 + 3] = __expf(d * Ac[q * 4 + 3]) * h[q * 4 + 3] + du * bv.w;
        }
    }
    ushort_t pb[16];
    #pragma unroll
    for (int n = 0; n < 16; ++n) pb[n] = f2b(h[n]);
    uint4* pp = (uint4*)(P + ((size_t)(b * NC + c) * ED + e) * NST);
    pp[0] = ((uint4*)pb)[0];
    pp[1] = ((uint4*)pb)[1];
    S[(size_t)(b * NC + c) * ED + e] = s;
}

__global__ __launch_bounds__(256) void k_scan2(ushort_t* __restrict__ P,
                                               const float* __restrict__ S,
                                               const float* __restrict__ A_log) {
    int i = blockIdx.x * 256 + threadIdx.x;
    int n = i & 15;
    int e = (i >> 4) & (ED - 1);
    int b = i >> 14;
    float Ac = -__expf(A_log[(size_t)e * NST + n]);
    float hin = 0.f;
    for (int c = 0; c < NC; ++c) {
        size_t base = (size_t)(b * NC + c) * ED + e;
        float p = b2f(P[base * NST + n]);
        float s = S[base];
        P[base * NST + n] = f2b(hin);
        hin = __expf(Ac * s) * hin + p;
    }
}

// scan3: re-scan with h_in using stored fp16 delta; fused silu(z); bf16 yb.
__global__ __launch_bounds__(256) void k_scan3(const float* __restrict__ xdb,
                                               const ushort_t* __restrict__ u,
                                               const ushort_t* __restrict__ xzb,
                                               const ushort_t* __restrict__ dyh,
                                               const float* __restrict__ A_log,
                                               const float* __restrict__ Dskip,
                                               const ushort_t* __restrict__ P,
                                               ushort_t* __restrict__ yb) {
    __shared__ float Xs[CS][XDBC];
    int tid = threadIdx.x;
    int e = ((blockIdx.x & 3) << 8) + tid;
    int c = (blockIdx.x >> 2) & (NC - 1);
    int b = blockIdx.x >> 9;
    size_t r0 = (size_t)b * LL + c * CS;
    {
        int t = tid >> 5, q = (tid & 31) * 2;
        *(float2*)&Xs[t][q] = *(const float2*)(xdb + (r0 + t) * XDBC + q);
    }
    float Ac[16];
    const float4* ap = (const float4*)(A_log + (size_t)e * NST);
    #pragma unroll
    for (int q = 0; q < 4; ++q) {
        float4 a = ap[q];
        Ac[q * 4 + 0] = -__expf(a.x); Ac[q * 4 + 1] = -__expf(a.y);
        Ac[q * 4 + 2] = -__expf(a.z); Ac[q * 4 + 3] = -__expf(a.w);
    }
    float h[16];
    const uint4* pp4 = (const uint4*)(P + ((size_t)(b * NC + c) * ED + e) * NST);
    uint4 pA = pp4[0], pB = pp4[1];
    const ushort_t* pw0 = (const ushort_t*)&pA;
    const ushort_t* pw1 = (const ushort_t*)&pB;
    #pragma unroll
    for (int n = 0; n < 8; ++n) { h[n] = b2f(pw0[n]); h[8 + n] = b2f(pw1[n]); }
    float Dk = Dskip[e];
    __syncthreads();
    const ushort_t* dp = dyh + r0 * ED + e;
    const ushort_t* up = u + r0 * ED + e;
    const ushort_t* zp = xzb + r0 * 2048 + 1024 + e;
    ushort_t* yp = yb + r0 * ED + e;
    for (int tt = 0; tt < CS; ++tt) {
        float d = h2f(dp[(size_t)tt * ED]);
        float uv = b2f(up[(size_t)tt * ED]);
        float zv = b2f(zp[(size_t)tt * 2048]);
        float du = d * uv;
        const float4* bp = (const float4*)&Xs[tt][DTR];
        const float4* cp = (const float4*)&Xs[tt][DTR + NST];
        float y = 0.f;
        #pragma unroll
        for (int q = 0; q < 4; ++q) {
            float4 bv = bp[q];
            float4 cv = cp[q];
            h[q * 4 + 0] = __expf(d * Ac[q * 4 + 0]) * h[q * 4 + 0] + du * bv.x;
            h[q * 4 + 1] = __expf(d * Ac[q * 4 + 1]) * h[q * 4 + 1] + du * bv.y;
            h[q * 4 + 2] = __expf(d * Ac[q * 4 + 2]) * h[q * 4 + 2] + du * bv.z;
            h[q * 4 + 3] = __expf(d * Ac[q * 4 + 3]) * h[q * 4 + 3] + du * bv.w;
            y += h[q * 4 + 0] * cv.x + h[q * 4 + 1] * cv.y +
                 h[q * 4 + 2] * cv.z + h[q * 4 + 3] * cv.w;
        }
        yp[(size_t)tt * ED] = f2b((y + Dk * uv) * silu_f(zv));
    }
}

extern "C" void kernel_launch(void* const* d_in, const int* in_sizes, int n_in,
                              void* d_out, int out_size, void* d_ws, size_t ws_size,
                              hipStream_t stream) {
    const float* x     = (const float*)d_in[0];
    const float* embW  = (const float*)d_in[1];
    const float* embB  = (const float*)d_in[2];
    const float* normw = (const float*)d_in[3];
    const float* ipW   = (const float*)d_in[4];
    const float* cW    = (const float*)d_in[5];
    const float* cb    = (const float*)d_in[6];
    const float* xpW   = (const float*)d_in[7];
    const float* dtW   = (const float*)d_in[8];
    const float* dtb   = (const float*)d_in[9];
    const float* Alog  = (const float*)d_in[10];
    const float* Dsk   = (const float*)d_in[11];
    const float* opW   = (const float*)d_in[12];
    const float* normfw= (const float*)d_in[13];
    float* out = (float*)d_out;

    // ws: h 8MB | xzb 16 | ub 8 | xdb 1 | Pp 16 (P bf16 16MB aliases it; live
    // ranges disjoint: Pp cxp->xred, P scan1->scan3) | S 2 | wip 4 | wop 2
    //     | yb 8  = 65 MB
    float* ws  = (float*)d_ws;
    float* h   = ws;
    ushort_t* xzb = (ushort_t*)(h + (size_t)BL * DM);
    ushort_t* ub  = xzb + (size_t)BL * 2 * ED;
    float* xdb = (float*)(ub + (size_t)BL * ED);
    float* Pp  = xdb + (size_t)BL * XDBC;                   // 16 MB
    float* S   = Pp + (size_t)XKS * BL * XDBC;
    ushort_t* wip = (ushort_t*)(S + (size_t)BB * NC * ED);
    ushort_t* wop = wip + (size_t)2 * 2 * ED * DM;
    ushort_t* yb  = wop + (size_t)2 * DM * ED;
    ushort_t* P   = (ushort_t*)Pp;      // bf16 chunk states (aliases Pp)
    ushort_t* hnb = (ushort_t*)d_out;   // bf16 rmsnorm scratch (d_out reuse)
    ushort_t* dyh = (ushort_t*)d_out;   // fp16 delta (post-bgemm0 window)

    int nEmb = BL * DM;
    int n1 = 2 * 2 * ED * DM / 4, n2 = 2 * DM * ED / 4;
    k_init<<<(nEmb + n1 + n2 + 255) / 256, 256, 0, stream>>>(
        x, embW, embB, h, ipW, opW, wip, wop, nEmb, n1, n2);

    for (int l = 0; l < 2; ++l) {
        const float* Al = Alog + (size_t)l * ED * NST;
        const float* dtWl = dtW + (size_t)l * ED * DTR;
        const float* dtbl = dtb + (size_t)l * ED;
        k_rmsnorm<1><<<BL, 256, 0, stream>>>(h, normw + (size_t)l * DM, hnb);
        k_bgemm<0, 1, 128><<<dim3(2 * ED / 128, BL / 128), 256, 0, stream>>>(
            hnb, wip + (size_t)l * 2 * ED * DM, nullptr, xzb, BL, 2 * ED, DM, DM, 2 * ED);
        k_cxp<<<dim3(XKS, BL / 64), 256, 0, stream>>>(
            xzb, cW + (size_t)l * ED * 4, cb + (size_t)l * ED,
            xpW + (size_t)l * XDBC * ED, ub, Pp);
        k_xred<<<BL * XDBC / 4 / 256, 256, 0, stream>>>(Pp, xdb);
        k_scan1<<<BB * NC * (ED / 256), 256, 0, stream>>>(
            xdb, ub, dtWl, dtbl, Al, P, S, dyh);
        k_scan2<<<BB * ED * NST / 256, 256, 0, stream>>>(P, S, Al);
        k_scan3<<<BB * NC * (ED / 256), 256, 0, stream>>>(
            xdb, ub, xzb, dyh, Al, Dsk + (size_t)l * ED, P, yb);
        k_bgemm<1, 0, 64><<<dim3(DM / 64, BL / 128), 256, 0, stream>>>(
            yb, wop + (size_t)l * DM * ED, h, h, BL, DM, ED, ED, DM);
    }
    k_rmsnorm<0><<<BL, 256, 0, stream>>>(h, normfw, out);
}

// Round 19
// 272.767 us; speedup vs baseline: 1.2961x; 1.0001x over previous
//
#include <hip/hip_runtime.h>
#include <math.h>
#include <stddef.h>

#define BB 4
#define LL 1024
#define DM 512
#define ED 1024
#define NST 16
#define DTR 32
#define XDBC 64
#define BL (BB*LL)   // 4096
#define CS 8         // scan chunk length
#define NC 128       // chunks per sequence (LL/CS)
#define XKS 16       // x_proj K-slices
#define XPAD 68      // x_proj LDS stride (floats)

typedef __attribute__((ext_vector_type(8))) short bf16x8;
typedef __attribute__((ext_vector_type(4))) float f32x4;
typedef unsigned short ushort_t;

__device__ __forceinline__ float silu_f(float x) { return x / (1.f + __expf(-x)); }

__device__ __forceinline__ ushort_t f2b(float f) {
    unsigned int u = __float_as_uint(f);
    unsigned int r = (u + 0x7FFFu + ((u >> 16) & 1u)) >> 16;
    return (ushort_t)r;
}
__device__ __forceinline__ float b2f(ushort_t v) {
    return __uint_as_float(((unsigned int)v) << 16);
}
__device__ __forceinline__ ushort_t f2h(float f) {
    _Float16 h = (_Float16)f;
    return *(ushort_t*)&h;
}
__device__ __forceinline__ float h2f(ushort_t v) {
    _Float16 h = *(_Float16*)&v;
    return (float)h;
}

__device__ __forceinline__ void gload16(const ushort_t* g, ushort_t* l) {
    __builtin_amdgcn_global_load_lds(
        (const __attribute__((address_space(1))) unsigned int*)g,
        (__attribute__((address_space(3))) unsigned int*)l, 16, 0, 0);
}

// ---------------- init: embedding + both weight cvt in one dispatch
__global__ void k_init(const float* __restrict__ x, const float* __restrict__ embW,
                       const float* __restrict__ embB, float* __restrict__ h,
                       const float* __restrict__ ipW, const float* __restrict__ opW,
                       ushort_t* __restrict__ wip, ushort_t* __restrict__ wop,
                       int nEmb, int n1, int n2) {
    int i = blockIdx.x * 256 + threadIdx.x;
    if (i < nEmb) {
        int d = i % DM, r = i / DM;
        h[i] = x[r * 2 + 0] * embW[d * 2 + 0] + x[r * 2 + 1] * embW[d * 2 + 1] + embB[d];
        return;
    }
    i -= nEmb;
    const float* src; ushort_t* dst; int q;
    if (i < n1) { src = ipW; dst = wip; q = i; }
    else if (i < n1 + n2) { src = opW; dst = wop; q = i - n1; }
    else return;
    float4 v = *(const float4*)(src + (size_t)q * 4);
    ushort_t o[4] = {f2b(v.x), f2b(v.y), f2b(v.z), f2b(v.w)};
    *(uint2*)(dst + (size_t)q * 4) = *(uint2*)o;
}

// ---------------- rmsnorm over rows of 512
template <int BF16OUT>
__global__ __launch_bounds__(256) void k_rmsnorm(const float* __restrict__ in,
                                                 const float* __restrict__ w,
                                                 void* __restrict__ outp) {
    int m = blockIdx.x;
    int tid = threadIdx.x;
    const float* row = in + (size_t)m * DM;
    float2 v = *(const float2*)(row + tid * 2);
    float ss = v.x * v.x + v.y * v.y;
    #pragma unroll
    for (int o = 32; o > 0; o >>= 1) ss += __shfl_down(ss, o, 64);
    __shared__ float red[4];
    int wid = tid >> 6;
    if ((tid & 63) == 0) red[wid] = ss;
    __syncthreads();
    float tot = red[0] + red[1] + red[2] + red[3];
    float rs = rsqrtf(tot * (1.f / DM) + 1e-5f);
    float2 wv = *(const float2*)(w + tid * 2);
    float ox = v.x * rs * wv.x;
    float oy = v.y * rs * wv.y;
    if (BF16OUT) {
        ushort_t o[2] = {f2b(ox), f2b(oy)};
        *(unsigned int*)((ushort_t*)outp + (size_t)m * DM + tid * 2) = *(unsigned int*)o;
    } else {
        *(float2*)((float*)outp + (size_t)m * DM + tid * 2) = make_float2(ox, oy);
    }
}

// ---------------- bf16 MFMA GEMM (round-12 structure, unchanged)
template <int ADDRES, int BF16OUT, int NT>
__global__ __launch_bounds__(256) void k_bgemm(const ushort_t* __restrict__ A,
                                               const ushort_t* __restrict__ W,
                                               const float* __restrict__ Res,
                                               void* __restrict__ C,
                                               int M, int N, int K, int lda, int ldc) {
    __shared__ ushort_t As[128 * 32];
    __shared__ ushort_t Bs[NT * 32];
    constexpr int NFJ = NT / 32;
    int tid = threadIdx.x;
    int bm = blockIdx.y * 128, bn = blockIdx.x * NT;
    int wave = tid >> 6, lane = tid & 63;
    int wr = wave >> 1, wc = wave & 1;
    int lr = lane & 15;
    int kc = lane >> 4;
    f32x4 acc[4][NFJ];
    #pragma unroll
    for (int i = 0; i < 4; ++i)
        #pragma unroll
        for (int j = 0; j < NFJ; ++j) acc[i][j] = (f32x4){0.f, 0.f, 0.f, 0.f};

    for (int k0 = 0; k0 < K; k0 += 32) {
        __syncthreads();
        #pragma unroll
        for (int ii = 0; ii < 2; ++ii) {
            int g = wave * 128 + ii * 64 + lane;
            int row = g >> 2;
            int c = (g & 3) ^ ((g >> 3) & 3);
            gload16(A + (size_t)(bm + row) * lda + k0 + c * 8,
                    As + (size_t)(wave * 128 + ii * 64) * 8);
        }
        #pragma unroll
        for (int ii = 0; ii < NFJ / 2; ++ii) {
            int g = wave * (NFJ / 2) * 64 + ii * 64 + lane;
            int row = g >> 2;
            int c = (g & 3) ^ ((g >> 3) & 3);
            gload16(W + (size_t)(bn + row) * K + k0 + c * 8,
                    Bs + (size_t)(wave * (NFJ / 2) * 64 + ii * 64) * 8);
        }
        __syncthreads();
        bf16x8 af[4], bfr[NFJ];
        #pragma unroll
        for (int i = 0; i < 4; ++i) {
            int ra = wr * 64 + i * 16 + lr;
            int ca = kc ^ ((ra >> 1) & 3);
            af[i] = *(const bf16x8*)(As + ra * 32 + ca * 8);
        }
        #pragma unroll
        for (int j = 0; j < NFJ; ++j) {
            int rb = wc * (NT / 2) + j * 16 + lr;
            int cb = kc ^ ((rb >> 1) & 3);
            bfr[j] = *(const bf16x8*)(Bs + rb * 32 + cb * 8);
        }
        #pragma unroll
        for (int i = 0; i < 4; ++i)
            #pragma unroll
            for (int j = 0; j < NFJ; ++j)
                acc[i][j] = __builtin_amdgcn_mfma_f32_16x16x32_bf16(af[i], bfr[j], acc[i][j], 0, 0, 0);
    }
    int crow0 = bm + wr * 64 + (lane >> 4) * 4;
    #pragma unroll
    for (int i = 0; i < 4; ++i)
        #pragma unroll
        for (int j = 0; j < NFJ; ++j)
            #pragma unroll
            for (int r = 0; r < 4; ++r) {
                size_t off = (size_t)(crow0 + i * 16 + r) * ldc + bn + wc * (NT / 2) + j * 16 + lr;
                float v = acc[i][j][r];
                if (ADDRES) v += Res[off];
                if (BF16OUT) ((ushort_t*)C)[off] = f2b(v);
                else         ((float*)C)[off] = v;
            }
}

// ---------------- fused conv+silu -> x_proj split-K partial (round-14 form)
__global__ __launch_bounds__(256) void k_cxp(const ushort_t* __restrict__ xzb,
                                             const float* __restrict__ cw,
                                             const float* __restrict__ cb,
                                             const float* __restrict__ xpW,
                                             ushort_t* __restrict__ ub,
                                             float* __restrict__ Pp) {
    __shared__ float As[64][XPAD];   // [e-within-slice][row]
    __shared__ float Ws[64][XPAD];   // [e-within-slice][n]
    int tid = threadIdx.x;
    int ks = blockIdx.x;
    int bm = blockIdx.y * 64;
    int ec0 = ks * 64;

    {
        int r0 = (tid >> 4) * 4;
        int e4 = (tid & 15) * 4;
        int e = ec0 + e4;
        float cw4[4][4], cb4[4];
        #pragma unroll
        for (int j = 0; j < 4; ++j) {
            float4 w = *(const float4*)(cw + (size_t)(e + j) * 4);
            cw4[j][0] = w.x; cw4[j][1] = w.y; cw4[j][2] = w.z; cw4[j][3] = w.w;
        }
        float4 cbv = *(const float4*)(cb + e);
        cb4[0] = cbv.x; cb4[1] = cbv.y; cb4[2] = cbv.z; cb4[3] = cbv.w;
        #pragma unroll
        for (int i = 0; i < 4; ++i) {
            int row = bm + r0 + i;
            int tloc = row & (LL - 1);
            const ushort_t* xrow = xzb + (size_t)row * 2048 + e;
            uint2 z2 = make_uint2(0, 0);
            uint2 v3 = *(const uint2*)xrow;
            uint2 v2 = (tloc >= 1) ? *(const uint2*)(xrow - 2048) : z2;
            uint2 v1 = (tloc >= 2) ? *(const uint2*)(xrow - 4096) : z2;
            uint2 v0 = (tloc >= 3) ? *(const uint2*)(xrow - 6144) : z2;
            const ushort_t* p0 = (const ushort_t*)&v0;
            const ushort_t* p1 = (const ushort_t*)&v1;
            const ushort_t* p2 = (const ushort_t*)&v2;
            const ushort_t* p3 = (const ushort_t*)&v3;
            ushort_t ures[4];
            #pragma unroll
            for (int j = 0; j < 4; ++j) {
                float a = cb4[j] + b2f(p0[j]) * cw4[j][0] + b2f(p1[j]) * cw4[j][1]
                                 + b2f(p2[j]) * cw4[j][2] + b2f(p3[j]) * cw4[j][3];
                float uu = silu_f(a);
                As[e4 + j][r0 + i] = uu;
                ures[j] = f2b(uu);
            }
            *(uint2*)(ub + (size_t)row * ED + e) = *(uint2*)ures;
        }
    }
    {
        int r = tid >> 2;
        int kc = (tid & 3) * 16;
        const float4* wp = (const float4*)(xpW + (size_t)r * ED + ec0 + kc);
        #pragma unroll
        for (int i = 0; i < 4; ++i) {
            float4 wv = wp[i];
            Ws[kc + i * 4 + 0][r] = wv.x; Ws[kc + i * 4 + 1][r] = wv.y;
            Ws[kc + i * 4 + 2][r] = wv.z; Ws[kc + i * 4 + 3][r] = wv.w;
        }
    }
    __syncthreads();
    int tm = (tid >> 4) * 4;
    int tn = (tid & 15) * 4;
    float acc[4][4] = {};
    #pragma unroll 4
    for (int k = 0; k < 64; ++k) {
        float4 a = *(const float4*)&As[k][tm];
        float4 b = *(const float4*)&Ws[k][tn];
        acc[0][0] += a.x * b.x; acc[0][1] += a.x * b.y; acc[0][2] += a.x * b.z; acc[0][3] += a.x * b.w;
        acc[1][0] += a.y * b.x; acc[1][1] += a.y * b.y; acc[1][2] += a.y * b.z; acc[1][3] += a.y * b.w;
        acc[2][0] += a.z * b.x; acc[2][1] += a.z * b.y; acc[2][2] += a.z * b.z; acc[2][3] += a.z * b.w;
        acc[3][0] += a.w * b.x; acc[3][1] += a.w * b.y; acc[3][2] += a.w * b.z; acc[3][3] += a.w * b.w;
    }
    float* pp = Pp + (size_t)ks * BL * XDBC;
    #pragma unroll
    for (int i = 0; i < 4; ++i)
        *(float4*)(pp + (size_t)(bm + tm + i) * XDBC + tn) =
            make_float4(acc[i][0], acc[i][1], acc[i][2], acc[i][3]);
}

// reduce 16 K-slice partials -> xdb
__global__ void k_xred(const float* __restrict__ Pp, float* __restrict__ xdb) {
    int i = blockIdx.x * 256 + threadIdx.x;
    float4 s = make_float4(0.f, 0.f, 0.f, 0.f);
    #pragma unroll
    for (int sl = 0; sl < XKS; ++sl) {
        float4 v = *(const float4*)(Pp + (size_t)sl * BL * XDBC + (size_t)i * 4);
        s.x += v.x; s.y += v.y; s.z += v.z; s.w += v.w;
    }
    *(float4*)(xdb + (size_t)i * 4) = s;
}

// ================ chunked selective scan (CS=8, NC=128) ================
// scan1: parallel delta precompute (stored fp16 for scan3), chunk-local scan,
// bf16 chunk states.
__global__ __launch_bounds__(256) void k_scan1(const float* __restrict__ xdb,
                                               const ushort_t* __restrict__ u,
                                               const float* __restrict__ dtW,
                                               const float* __restrict__ dtb,
                                               const float* __restrict__ A_log,
                                               ushort_t* __restrict__ P,
                                               float* __restrict__ S,
                                               ushort_t* __restrict__ dyh) {
    __shared__ float Xs[CS][XDBC];   // 2 KB
    int tid = threadIdx.x;
    int e = ((blockIdx.x & 3) << 8) + tid;
    int c = (blockIdx.x >> 2) & (NC - 1);
    int b = blockIdx.x >> 9;
    size_t r0 = (size_t)b * LL + c * CS;
    {
        int t = tid >> 5, q = (tid & 31) * 2;
        *(float2*)&Xs[t][q] = *(const float2*)(xdb + (r0 + t) * XDBC + q);
    }
    float Ac[16];
    const float4* ap = (const float4*)(A_log + (size_t)e * NST);
    #pragma unroll
    for (int q = 0; q < 4; ++q) {
        float4 a = ap[q];
        Ac[q * 4 + 0] = -__expf(a.x); Ac[q * 4 + 1] = -__expf(a.y);
        Ac[q * 4 + 2] = -__expf(a.z); Ac[q * 4 + 3] = -__expf(a.w);
    }
    float dtw[32];
    const float4* wq = (const float4*)(dtW + (size_t)e * DTR);
    #pragma unroll
    for (int q = 0; q < 8; ++q) {
        float4 w = wq[q];
        dtw[q * 4 + 0] = w.x; dtw[q * 4 + 1] = w.y;
        dtw[q * 4 + 2] = w.z; dtw[q * 4 + 3] = w.w;
    }
    float bias = dtb[e];
    __syncthreads();
    float dv[CS];
    #pragma unroll
    for (int t = 0; t < CS; ++t) {
        float acc = bias;
        #pragma unroll
        for (int q = 0; q < 8; ++q) {
            float4 d = *(const float4*)&Xs[t][q * 4];
            acc += d.x * dtw[q * 4 + 0] + d.y * dtw[q * 4 + 1] +
                   d.z * dtw[q * 4 + 2] + d.w * dtw[q * 4 + 3];
        }
        dv[t] = (acc > 20.f) ? acc : __logf(1.f + __expf(acc));
        dyh[(r0 + t) * ED + e] = f2h(dv[t]);
    }
    float h[16] = {};
    float s = 0.f;
    const ushort_t* up = u + r0 * ED + e;
    for (int tt = 0; tt < CS; ++tt) {
        float d = dv[tt];
        float uv = b2f(up[(size_t)tt * ED]);
        s += d;
        float du = d * uv;
        const float4* bp = (const float4*)&Xs[tt][DTR];
        #pragma unroll
        for (int q = 0; q < 4; ++q) {
            float4 bv = bp[q];
            h[q * 4 + 0] = __expf(d * Ac[q * 4 + 0]) * h[q * 4 + 0] + du * bv.x;
            h[q * 4 + 1] = __expf(d * Ac[q * 4 + 1]) * h[q * 4 + 1] + du * bv.y;
            h[q * 4 + 2] = __expf(d * Ac[q * 4 + 2]) * h[q * 4 + 2] + du * bv.z;
            h[q * 4 + 3] = __expf(d * Ac[q * 4 + 3]) * h[q * 4 + 3] + du * bv.w;
        }
    }
    ushort_t pb[16];
    #pragma unroll
    for (int n = 0; n < 16; ++n) pb[n] = f2b(h[n]);
    uint4* pp = (uint4*)(P + ((size_t)(b * NC + c) * ED + e) * NST);
    pp[0] = ((uint4*)pb)[0];
    pp[1] = ((uint4*)pb)[1];
    S[(size_t)(b * NC + c) * ED + e] = s;
}

__global__ __launch_bounds__(256) void k_scan2(ushort_t* __restrict__ P,
                                               const float* __restrict__ S,
                                               const float* __restrict__ A_log) {
    int i = blockIdx.x * 256 + threadIdx.x;
    int n = i & 15;
    int e = (i >> 4) & (ED - 1);
    int b = i >> 14;
    float Ac = -__expf(A_log[(size_t)e * NST + n]);
    float hin = 0.f;
    for (int c = 0; c < NC; ++c) {
        size_t base = (size_t)(b * NC + c) * ED + e;
        float p = b2f(P[base * NST + n]);
        float s = S[base];
        P[base * NST + n] = f2b(hin);
        hin = __expf(Ac * s) * hin + p;
    }
}

// scan3: re-scan with h_in using stored fp16 delta; fused silu(z); bf16 yb.
__global__ __launch_bounds__(256) void k_scan3(const float* __restrict__ xdb,
                                               const ushort_t* __restrict__ u,
                                               const ushort_t* __restrict__ xzb,
                                               const ushort_t* __restrict__ dyh,
                                               const float* __restrict__ A_log,
                                               const float* __restrict__ Dskip,
                                               const ushort_t* __restrict__ P,
                                               ushort_t* __restrict__ yb) {
    __shared__ float Xs[CS][XDBC];
    int tid = threadIdx.x;
    int e = ((blockIdx.x & 3) << 8) + tid;
    int c = (blockIdx.x >> 2) & (NC - 1);
    int b = blockIdx.x >> 9;
    size_t r0 = (size_t)b * LL + c * CS;
    {
        int t = tid >> 5, q = (tid & 31) * 2;
        *(float2*)&Xs[t][q] = *(const float2*)(xdb + (r0 + t) * XDBC + q);
    }
    float Ac[16];
    const float4* ap = (const float4*)(A_log + (size_t)e * NST);
    #pragma unroll
    for (int q = 0; q < 4; ++q) {
        float4 a = ap[q];
        Ac[q * 4 + 0] = -__expf(a.x); Ac[q * 4 + 1] = -__expf(a.y);
        Ac[q * 4 + 2] = -__expf(a.z); Ac[q * 4 + 3] = -__expf(a.w);
    }
    float h[16];
    const uint4* pp4 = (const uint4*)(P + ((size_t)(b * NC + c) * ED + e) * NST);
    uint4 pA = pp4[0], pB = pp4[1];
    const ushort_t* pw0 = (const ushort_t*)&pA;
    const ushort_t* pw1 = (const ushort_t*)&pB;
    #pragma unroll
    for (int n = 0; n < 8; ++n) { h[n] = b2f(pw0[n]); h[8 + n] = b2f(pw1[n]); }
    float Dk = Dskip[e];
    __syncthreads();
    const ushort_t* dp = dyh + r0 * ED + e;
    const ushort_t* up = u + r0 * ED + e;
    const ushort_t* zp = xzb + r0 * 2048 + 1024 + e;
    ushort_t* yp = yb + r0 * ED + e;
    for (int tt = 0; tt < CS; ++tt) {
        float d = h2f(dp[(size_t)tt * ED]);
        float uv = b2f(up[(size_t)tt * ED]);
        float zv = b2f(zp[(size_t)tt * 2048]);
        float du = d * uv;
        const float4* bp = (const float4*)&Xs[tt][DTR];
        const float4* cp = (const float4*)&Xs[tt][DTR + NST];
        float y = 0.f;
        #pragma unroll
        for (int q = 0; q < 4; ++q) {
            float4 bv = bp[q];
            float4 cv = cp[q];
            h[q * 4 + 0] = __expf(d * Ac[q * 4 + 0]) * h[q * 4 + 0] + du * bv.x;
            h[q * 4 + 1] = __expf(d * Ac[q * 4 + 1]) * h[q * 4 + 1] + du * bv.y;
            h[q * 4 + 2] = __expf(d * Ac[q * 4 + 2]) * h[q * 4 + 2] + du * bv.z;
            h[q * 4 + 3] = __expf(d * Ac[q * 4 + 3]) * h[q * 4 + 3] + du * bv.w;
            y += h[q * 4 + 0] * cv.x + h[q * 4 + 1] * cv.y +
                 h[q * 4 + 2] * cv.z + h[q * 4 + 3] * cv.w;
        }
        yp[(size_t)tt * ED] = f2b((y + Dk * uv) * silu_f(zv));
    }
}

extern "C" void kernel_launch(void* const* d_in, const int* in_sizes, int n_in,
                              void* d_out, int out_size, void* d_ws, size_t ws_size,
                              hipStream_t stream) {
    const float* x     = (const float*)d_in[0];
    const float* embW  = (const float*)d_in[1];
    const float* embB  = (const float*)d_in[2];
    const float* normw = (const float*)d_in[3];
    const float* ipW   = (const float*)d_in[4];
    const float* cW    = (const float*)d_in[5];
    const float* cb    = (const float*)d_in[6];
    const float* xpW   = (const float*)d_in[7];
    const float* dtW   = (const float*)d_in[8];
    const float* dtb   = (const float*)d_in[9];
    const float* Alog  = (const float*)d_in[10];
    const float* Dsk   = (const float*)d_in[11];
    const float* opW   = (const float*)d_in[12];
    const float* normfw= (const float*)d_in[13];
    float* out = (float*)d_out;

    // ws: h 8MB | xzb 16 | ub 8 | xdb 1 | Pp 16 (P bf16 16MB aliases it; live
    // ranges disjoint: Pp cxp->xred, P scan1->scan3) | S 2 | wip 4 | wop 2
    //     | yb 8  = 65 MB
    float* ws  = (float*)d_ws;
    float* h   = ws;
    ushort_t* xzb = (ushort_t*)(h + (size_t)BL * DM);
    ushort_t* ub  = xzb + (size_t)BL * 2 * ED;
    float* xdb = (float*)(ub + (size_t)BL * ED);
    float* Pp  = xdb + (size_t)BL * XDBC;                   // 16 MB
    float* S   = Pp + (size_t)XKS * BL * XDBC;
    ushort_t* wip = (ushort_t*)(S + (size_t)BB * NC * ED);
    ushort_t* wop = wip + (size_t)2 * 2 * ED * DM;
    ushort_t* yb  = wop + (size_t)2 * DM * ED;
    ushort_t* P   = (ushort_t*)Pp;      // bf16 chunk states (aliases Pp)
    ushort_t* hnb = (ushort_t*)d_out;   // bf16 rmsnorm scratch (d_out reuse)
    ushort_t* dyh = (ushort_t*)d_out;   // fp16 delta (post-bgemm0 window)

    int nEmb = BL * DM;
    int n1 = 2 * 2 * ED * DM / 4, n2 = 2 * DM * ED / 4;
    k_init<<<(nEmb + n1 + n2 + 255) / 256, 256, 0, stream>>>(
        x, embW, embB, h, ipW, opW, wip, wop, nEmb, n1, n2);

    for (int l = 0; l < 2; ++l) {
        const float* Al = Alog + (size_t)l * ED * NST;
        const float* dtWl = dtW + (size_t)l * ED * DTR;
        const float* dtbl = dtb + (size_t)l * ED;
        k_rmsnorm<1><<<BL, 256, 0, stream>>>(h, normw + (size_t)l * DM, hnb);
        k_bgemm<0, 1, 128><<<dim3(2 * ED / 128, BL / 128), 256, 0, stream>>>(
            hnb, wip + (size_t)l * 2 * ED * DM, nullptr, xzb, BL, 2 * ED, DM, DM, 2 * ED);
        k_cxp<<<dim3(XKS, BL / 64), 256, 0, stream>>>(
            xzb, cW + (size_t)l * ED * 4, cb + (size_t)l * ED,
            xpW + (size_t)l * XDBC * ED, ub, Pp);
        k_xred<<<BL * XDBC / 4 / 256, 256, 0, stream>>>(Pp, xdb);
        k_scan1<<<BB * NC * (ED / 256), 256, 0, stream>>>(
            xdb, ub, dtWl, dtbl, Al, P, S, dyh);
        k_scan2<<<BB * ED * NST / 256, 256, 0, stream>>>(P, S, Al);
        k_scan3<<<BB * NC * (ED / 256), 256, 0, stream>>>(
            xdb, ub, xzb, dyh, Al, Dsk + (size_t)l * ED, P, yb);
        k_bgemm<1, 0, 64><<<dim3(DM / 64, BL / 128), 256, 0, stream>>>(
            yb, wop + (size_t)l * DM * ED, h, h, BL, DM, ED, ED, DM);
    }
    k_rmsnorm<0><<<BL, 256, 0, stream>>>(h, normfw, out);
}